// Round 21
// baseline (57.174 us; speedup 1.0000x reference)
//
#include <hip/hip_runtime.h>
#include <cstddef>

#define HDIM 2048
#define NE 64
#define TOPK 4
#define BM2 32

typedef short bf16x8 __attribute__((ext_vector_type(8)));
typedef float f32x4 __attribute__((ext_vector_type(4)));

// Exact 3-way bf16 truncation split: a = f(h0) + f(h1) + f(h2) (24 mantissa bits).
__device__ __forceinline__ void split3(float a, unsigned short& h0,
                                       unsigned short& h1, unsigned short& h2) {
    unsigned int u = __float_as_uint(a);
    h0 = (unsigned short)(u >> 16);
    float f0 = __uint_as_float(u & 0xffff0000u);
    float r1 = a - f0;
    unsigned int v = __float_as_uint(r1);
    h1 = (unsigned short)(v >> 16);
    float f1 = __uint_as_float(v & 0xffff0000u);
    float r2 = r1 - f1;
    h2 = (unsigned short)(__float_as_uint(r2) >> 16);
}

// ---------- prepass (r16-proven, unchanged): B fragments, 3 bf16 planes ----------
// wtb[plane][s(64)][n(4)][lane(64)][j(8)]: e = 16n + (lane&15), k = 32s + 8*(lane>>4) + j
__global__ __launch_bounds__(256) void prep_b_kernel(
    const float* __restrict__ w, const float* __restrict__ scale,
    unsigned short* __restrict__ wtb)
{
    const int s = blockIdx.x;          // 0..63
    const int n = threadIdx.x >> 6;    // 0..3
    const int l = threadIdx.x & 63;
    const int e = 16 * n + (l & 15);
    const int k = 32 * s + 8 * (l >> 4);
    unsigned short h0[8], h1[8], h2[8];
    #pragma unroll
    for (int j = 0; j < 8; ++j) {
        float v = w[(size_t)e * HDIM + k + j] * scale[k + j];
        split3(v, h0[j], h1[j], h2[j]);
    }
    size_t off = ((size_t)s * 4 + n) * 512 + (size_t)l * 8;
    #pragma unroll
    for (int j = 0; j < 8; ++j) {
        wtb[off + j]          = h0[j];
        wtb[131072 + off + j] = h1[j];
        wtb[262144 + off + j] = h2[j];
    }
}

// ---------- main: LDS-free barrier-free MFMA partials at 16 waves/CU ----------
// 256 thr = 4 waves (kh 0..3); KSPLIT=2 across blocks -> grid 1024 = 4 blocks/CU.
// Per wave: 32 tok x 64 exp x (512/KSPLIT) K, r17's proven inner structure.
// Each wave writes its raw partial (index p = khalf*4+kh) + ssq partial to ws.
template<int KSPLIT>
__global__ __launch_bounds__(256) void gemm21_kernel(
    const float* __restrict__ x, const unsigned short* __restrict__ wtb,
    float* __restrict__ sp0,     // partial p=0 (probs region)
    float* __restrict__ spws,    // partials p=1..4*KSPLIT-1
    float* __restrict__ sq,      // [4*KSPLIT][tokens] ssq partials
    int tokens)
{
    constexpr int NST = 16 / KSPLIT;   // ksteps per wave (of 32 k each)
    const int tid = threadIdx.x;
    const int kh = tid >> 6;           // wave id 0..3
    const int l = tid & 63;
    const int khalf = (KSPLIT == 2) ? (blockIdx.x & 1) : 0;
    const int tok0 = ((KSPLIT == 2) ? (blockIdx.x >> 1) : blockIdx.x) * 32;
    const int p = khalf * 4 + kh;      // partial index
    const int k0 = p * (NST * 32);     // this wave's K base
    const int m = l & 15;              // A row / B col within tile
    const int g = l >> 4;              // k-group

    const float* xr0 = x + (size_t)(tok0 + m) * HDIM + k0 + 8 * g;   // tile 0
    const float* xr1 = xr0 + (size_t)16 * HDIM;                       // tile 1
    const unsigned short* wb = wtb + (size_t)(p * NST) * 2048 + (size_t)l * 8;

    f32x4 acc0[4], acc1[4];
    #pragma unroll
    for (int n = 0; n < 4; ++n) {
        acc0[n] = (f32x4){0.f, 0.f, 0.f, 0.f};
        acc1[n] = (f32x4){0.f, 0.f, 0.f, 0.f};
    }
    float ssq0 = 0.f, ssq1 = 0.f;

    float4 Aq[2][4];                   // A dbuf: [buf][tile*2 + half]
    bf16x8 Bb[2][12];                  // B dbuf: [buf][3n+plane]

#define LOADA(buf, s) { \
        Aq[buf][0] = *(const float4*)(xr0 + 32 * (s)); \
        Aq[buf][1] = *(const float4*)(xr0 + 32 * (s) + 4); \
        Aq[buf][2] = *(const float4*)(xr1 + 32 * (s)); \
        Aq[buf][3] = *(const float4*)(xr1 + 32 * (s) + 4); }
#define LOADB(buf, s) { \
        const unsigned short* bs_ = wb + (size_t)(s) * 2048; \
        _Pragma("unroll") \
        for (int n = 0; n < 4; ++n) { \
            Bb[buf][3*n + 0] = *(const bf16x8*)(bs_ + n * 512); \
            Bb[buf][3*n + 1] = *(const bf16x8*)(bs_ + n * 512 + 131072); \
            Bb[buf][3*n + 2] = *(const bf16x8*)(bs_ + n * 512 + 262144); } }

    LOADA(0, 0);
    LOADB(0, 0);

    #pragma unroll
    for (int s = 0; s < NST; ++s) {
        const int cur = s & 1, nxt = cur ^ 1;
        if (s + 1 < NST) { LOADA(nxt, s + 1); LOADB(nxt, s + 1); }  // next kstep in flight

        float af0[8], af1[8];
        *(float4*)af0 = Aq[cur][0]; *(float4*)(af0 + 4) = Aq[cur][1];
        *(float4*)af1 = Aq[cur][2]; *(float4*)(af1 + 4) = Aq[cur][3];
        unsigned short p0[8], p1[8], p2[8], q0[8], q1[8], q2[8];
        #pragma unroll
        for (int j = 0; j < 8; ++j) {
            split3(af0[j], p0[j], p1[j], p2[j]);
            split3(af1[j], q0[j], q1[j], q2[j]);
            ssq0 = fmaf(af0[j], af0[j], ssq0);
            ssq1 = fmaf(af1[j], af1[j], ssq1);
        }
        bf16x8 a0, a1, a2, c0, c1, c2;
        #pragma unroll
        for (int j = 0; j < 8; ++j) {
            a0[j] = (short)p0[j]; a1[j] = (short)p1[j]; a2[j] = (short)p2[j];
            c0[j] = (short)q0[j]; c1[j] = (short)q1[j]; c2[j] = (short)q2[j];
        }
        __builtin_amdgcn_s_setprio(1);
        #pragma unroll
        for (int n = 0; n < 4; ++n) {
            bf16x8 b0 = Bb[cur][3*n + 0];
            bf16x8 b1 = Bb[cur][3*n + 1];
            bf16x8 b2 = Bb[cur][3*n + 2];
            acc0[n] = __builtin_amdgcn_mfma_f32_16x16x32_bf16(a0, b0, acc0[n], 0, 0, 0);
            acc0[n] = __builtin_amdgcn_mfma_f32_16x16x32_bf16(a0, b1, acc0[n], 0, 0, 0);
            acc0[n] = __builtin_amdgcn_mfma_f32_16x16x32_bf16(a1, b0, acc0[n], 0, 0, 0);
            acc0[n] = __builtin_amdgcn_mfma_f32_16x16x32_bf16(a1, b1, acc0[n], 0, 0, 0);
            acc0[n] = __builtin_amdgcn_mfma_f32_16x16x32_bf16(a0, b2, acc0[n], 0, 0, 0);
            acc0[n] = __builtin_amdgcn_mfma_f32_16x16x32_bf16(a2, b0, acc0[n], 0, 0, 0);
            acc1[n] = __builtin_amdgcn_mfma_f32_16x16x32_bf16(c0, b0, acc1[n], 0, 0, 0);
            acc1[n] = __builtin_amdgcn_mfma_f32_16x16x32_bf16(c0, b1, acc1[n], 0, 0, 0);
            acc1[n] = __builtin_amdgcn_mfma_f32_16x16x32_bf16(c1, b0, acc1[n], 0, 0, 0);
            acc1[n] = __builtin_amdgcn_mfma_f32_16x16x32_bf16(c1, b1, acc1[n], 0, 0, 0);
            acc1[n] = __builtin_amdgcn_mfma_f32_16x16x32_bf16(c0, b2, acc1[n], 0, 0, 0);
            acc1[n] = __builtin_amdgcn_mfma_f32_16x16x32_bf16(c2, b0, acc1[n], 0, 0, 0);
        }
        __builtin_amdgcn_s_setprio(0);
    }
#undef LOADA
#undef LOADB

    // ssq: sum the 4 k-group lanes per token (lanes differ in bits 4,5)
    ssq0 += __shfl_xor(ssq0, 16, 64);
    ssq0 += __shfl_xor(ssq0, 32, 64);
    ssq1 += __shfl_xor(ssq1, 16, 64);
    ssq1 += __shfl_xor(ssq1, 32, 64);
    if (g == 0) {
        sq[(size_t)p * tokens + tok0 + m]      = ssq0;
        sq[(size_t)p * tokens + tok0 + 16 + m] = ssq1;
    }

    // raw partial write (D: col=lane&15, row=4*(lane>>4)+reg [m89])
    float* sp = (p == 0) ? sp0 : (spws + (size_t)(p - 1) * tokens * NE);
    #pragma unroll
    for (int n = 0; n < 4; ++n)
        #pragma unroll
        for (int r = 0; r < 4; ++r) {
            sp[(size_t)(tok0 + 4 * g + r) * NE + 16 * n + m]      = acc0[n][r];
            sp[(size_t)(tok0 + 16 + 4 * g + r) * NE + 16 * n + m] = acc1[n][r];
        }
}

// ---------- finisher (r13-proven verbatim): tree-sum partials, rmsnorm, softmax, top-4 ----------
template<int KS>
__global__ __launch_bounds__(256) void finish21_kernel(
    const float* __restrict__ sp0, const float* __restrict__ spws,
    const float* __restrict__ sq, const float* __restrict__ pes,
    float* __restrict__ probs, float* __restrict__ tkw, float* __restrict__ tki,
    int tokens)
{
    __shared__ float Sl[BM2 * 65];
    __shared__ float Pl[BM2 * 65];
    __shared__ float FN[BM2];
    __shared__ float RS[BM2];

    const int tid = threadIdx.x;
    const int tok0 = blockIdx.x * BM2;

    if (tid < BM2) {
        float q[KS];
        #pragma unroll
        for (int i = 0; i < KS; i++) q[i] = sq[(size_t)i * tokens + tok0 + tid];
        #pragma unroll
        for (int st = 1; st < KS; st <<= 1)
            #pragma unroll
            for (int i = 0; i < KS; i += 2 * st) q[i] += q[i + st];
        FN[tid] = rsqrtf(q[0] * (1.0f / HDIM) + 1e-6f) * 0.022097086912079612f;
    }
    __syncthreads();

    #pragma unroll
    for (int qq = 0; qq < 2; qq++) {
        int f = tid + 256 * qq;
        int mr = f >> 4;
        int e4 = f & 15;
        float4 t[KS];
        t[0] = ((const float4*)sp0)[(size_t)(tok0 + mr) * (NE / 4) + e4];
        #pragma unroll
        for (int i = 1; i < KS; i++)
            t[i] = ((const float4*)(spws + (size_t)(i - 1) * tokens * NE))
                       [(size_t)(tok0 + mr) * (NE / 4) + e4];
        #pragma unroll
        for (int st = 1; st < KS; st <<= 1)
            #pragma unroll
            for (int i = 0; i < KS; i += 2 * st) {
                t[i].x += t[i + st].x; t[i].y += t[i + st].y;
                t[i].z += t[i + st].z; t[i].w += t[i + st].w;
            }
        float fn = FN[mr];
        int base = mr * 65 + e4 * 4;
        Sl[base + 0] = t[0].x * fn; Sl[base + 1] = t[0].y * fn;
        Sl[base + 2] = t[0].z * fn; Sl[base + 3] = t[0].w * fn;
    }
    __syncthreads();

    if (tid < BM2) {
        const int mm = tid;
        float mx = -3.0e38f;
        for (int e = 0; e < NE; e++) mx = fmaxf(mx, Sl[mm * 65 + e]);
        float sum = 0.f;
        for (int e = 0; e < NE; e++) {
            float pp = __expf(Sl[mm * 65 + e] - mx);
            Pl[mm * 65 + e] = pp;
            sum += pp;
        }
        RS[mm] = 1.0f / sum;
    }
    __syncthreads();

    #pragma unroll
    for (int qq = 0; qq < 2; qq++) {
        int f = tid + 256 * qq;
        int mr = f >> 4;
        int e0 = (f & 15) * 4;
        float rs = RS[mr];
        float4 pv;
        pv.x = Pl[mr * 65 + e0 + 0] * rs;
        pv.y = Pl[mr * 65 + e0 + 1] * rs;
        pv.z = Pl[mr * 65 + e0 + 2] * rs;
        pv.w = Pl[mr * 65 + e0 + 3] * rs;
        *(float4*)&probs[(size_t)(tok0 + mr) * NE + e0] = pv;
    }

    if (tid < BM2) {                   // destructive top-4, lowest-index ties
        const int mm = tid;
        float wv[TOPK]; int idx[TOPK];
        float wsum = 0.f;
        #pragma unroll
        for (int kk = 0; kk < TOPK; ++kk) {
            float best = -3.0e38f; int bi = 0;
            for (int e = 0; e < NE; e++) {
                float v = Sl[mm * 65 + e];
                if (v > best) { best = v; bi = e; }
            }
            Sl[mm * 65 + bi] = -3.4e38f;
            float pp = Pl[mm * 65 + bi];
            wv[kk] = pp; idx[kk] = bi; wsum += pp;
        }
        float inv = 1.0f / wsum;
        size_t ob = (size_t)(tok0 + mm) * TOPK;
        #pragma unroll
        for (int kk = 0; kk < TOPK; kk++) {
            tkw[ob + kk] = wv[kk] * inv * pes[idx[kk]];
            tki[ob + kk] = (float)idx[kk];   // harness reads flat buffer as float32
        }
    }
}

extern "C" void kernel_launch(void* const* d_in, const int* in_sizes, int n_in,
                              void* d_out, int out_size, void* d_ws, size_t ws_size,
                              hipStream_t stream) {
    const float* x     = (const float*)d_in[0];
    const float* w     = (const float*)d_in[1];
    const float* scale = (const float*)d_in[2];
    const float* pes   = (const float*)d_in[3];
    const int tokens = in_sizes[0] / HDIM;      // 16384

    float* probs = (float*)d_out;
    float* tkw   = probs + (size_t)tokens * NE;
    float* tki   = tkw + (size_t)tokens * TOPK;

    // ws: wtb (768 KB = 196608 float-equivalents) | spws (KS-1 partials) | sq (KS x tokens)
    const size_t wtbF = 196608;                  // 3*131072 shorts / 2
    const size_t spN  = (size_t)tokens * NE;
    unsigned short* wtb = (unsigned short*)d_ws;
    auto need = [&](int kp) {
        return (wtbF + (size_t)(4 * kp - 1) * spN + (size_t)(4 * kp) * tokens) * sizeof(float);
    };
    const int KSPLIT = (ws_size >= need(2)) ? 2 : 1;   // r11 proved ws >= 64 MB; need(2) ~30.7 MB

    float* spws = (float*)d_ws + wtbF;
    float* sq   = spws + (size_t)(4 * KSPLIT - 1) * spN;
    float* sp0  = probs;                         // partial 0 in probs region; finisher overwrites

    prep_b_kernel<<<HDIM / 32, 256, 0, stream>>>(w, scale, wtb);

    const int grid1 = (tokens / 32) * KSPLIT;    // 1024 @ KSPLIT=2 -> 4 blocks/CU, 16 waves/CU
    if (KSPLIT == 2)
        gemm21_kernel<2><<<grid1, 256, 0, stream>>>(x, wtb, sp0, spws, sq, tokens);
    else
        gemm21_kernel<1><<<grid1, 256, 0, stream>>>(x, wtb, sp0, spws, sq, tokens);

    const int grid2 = tokens / BM2;              // 512
    if (KSPLIT == 2)
        finish21_kernel<8><<<grid2, 256, 0, stream>>>(sp0, spws, sq, pes, probs, tkw, tki, tokens);
    else
        finish21_kernel<4><<<grid2, 256, 0, stream>>>(sp0, spws, sq, pes, probs, tkw, tki, tokens);
}

// Round 24
// 41.344 us; speedup vs baseline: 1.3829x; 1.3829x over previous
//
#include <hip/hip_runtime.h>
#include <cstddef>

#define HDIM 2048
#define NE 64
#define TOPK 4

typedef short short8 __attribute__((ext_vector_type(8)));
typedef float f32x4 __attribute__((ext_vector_type(4)));

// fp16 round-to-nearest 2-way split with scaled residual plane:
// a = (float)h0 + (float)h1 * 2^-12, error ~ |a|*2^-24.
__device__ __forceinline__ void split2u(float a, unsigned short& h0, unsigned short& h1) {
    _Float16 x0 = (_Float16)a;
    float r = a - (float)x0;
    _Float16 x1 = (_Float16)(r * 4096.0f);
    h0 = __builtin_bit_cast(unsigned short, x0);
    h1 = __builtin_bit_cast(unsigned short, x1);
}

// MFMA wrapper: raw short8 bit-patterns, bitcast to f16 vectors at the call.
__device__ __forceinline__ f32x4 mfma_f16(short8 a, short8 b, f32x4 c) {
    typedef _Float16 f16x8_t __attribute__((ext_vector_type(8)));
    return __builtin_amdgcn_mfma_f32_16x16x32_f16(
        __builtin_bit_cast(f16x8_t, a), __builtin_bit_cast(f16x8_t, b), c, 0, 0, 0);
}

// ---------- prepass: B fragments, 2 fp16 planes (b0, b1*2^12) as ushort ----------
// wtb[plane][s(64)][n(4)][lane(64)][j(8)]: e = 16n + (lane&15), k = 32s + 8*(lane>>4) + j
__global__ __launch_bounds__(256) void prep_b_kernel(
    const float* __restrict__ w, const float* __restrict__ scale,
    unsigned short* __restrict__ wtb)
{
    const int s = blockIdx.x;          // 0..63
    const int n = threadIdx.x >> 6;    // 0..3
    const int l = threadIdx.x & 63;
    const int e = 16 * n + (l & 15);
    const int k = 32 * s + 8 * (l >> 4);
    unsigned short h0[8], h1[8];
    #pragma unroll
    for (int j = 0; j < 8; ++j) {
        float v = w[(size_t)e * HDIM + k + j] * scale[k + j];
        split2u(v, h0[j], h1[j]);
    }
    size_t off = ((size_t)s * 4 + n) * 512 + (size_t)l * 8;
    #pragma unroll
    for (int j = 0; j < 8; ++j) {
        wtb[off + j]          = h0[j];
        wtb[131072 + off + j] = h1[j];
    }
}

// ---------- fused: fp16 split-2 (3 MFMA per tile-n), r17-proven skeleton ----------
// Block = 32 tokens, 4 waves = K-quarters (kh=0..3, 16 ksteps each), grid 512.
// Per wave: 32 tok x 64 exp x 512 K. accH (scale 1) + accL (scale 2^-12).
// r22/r23 bug fixed: combine + probs-write loops now cover all 512 float4
// (f = tid + 256*qq, qq<2) — they covered only tokens 0-15 with 256 threads.
__global__ __launch_bounds__(256) void fused_router_kernel(
    const float* __restrict__ x, const unsigned short* __restrict__ wtb,
    const float* __restrict__ pes,
    float* __restrict__ probs, float* __restrict__ tkw, float* __restrict__ tki)
{
    __shared__ float Sp[4][32 * 65];   // per-kh score partials
    __shared__ float Pl[32 * 65];
    __shared__ float SQp[4][32];
    __shared__ float FN[32];
    __shared__ float RS[32];

    const int tid = threadIdx.x;
    const int kh = tid >> 6;           // K-quarter 0..3
    const int l = tid & 63;
    const int tok0 = blockIdx.x * 32;
    const int m = l & 15;              // A row / B col within tile
    const int g = l >> 4;              // k-group

    const float* xr0 = x + (size_t)(tok0 + m) * HDIM + 512 * kh + 8 * g;   // tile 0
    const float* xr1 = xr0 + (size_t)16 * HDIM;                             // tile 1
    const unsigned short* wb = wtb + (size_t)(16 * kh) * 2048 + (size_t)l * 8;

    f32x4 accH0[4], accL0[4], accH1[4], accL1[4];
    #pragma unroll
    for (int n = 0; n < 4; ++n) {
        accH0[n] = (f32x4){0.f, 0.f, 0.f, 0.f};
        accL0[n] = (f32x4){0.f, 0.f, 0.f, 0.f};
        accH1[n] = (f32x4){0.f, 0.f, 0.f, 0.f};
        accL1[n] = (f32x4){0.f, 0.f, 0.f, 0.f};
    }
    float ssq0 = 0.f, ssq1 = 0.f;

    float4 Aq[2][4];                   // A dbuf: [buf][tile*2 + half]
    short8 Bb[2][8];                   // B dbuf: [buf][2n + plane]

#define LOADA(buf, s) { \
        Aq[buf][0] = *(const float4*)(xr0 + 32 * (s)); \
        Aq[buf][1] = *(const float4*)(xr0 + 32 * (s) + 4); \
        Aq[buf][2] = *(const float4*)(xr1 + 32 * (s)); \
        Aq[buf][3] = *(const float4*)(xr1 + 32 * (s) + 4); }
#define LOADB(buf, s) { \
        const unsigned short* bs_ = wb + (size_t)(s) * 2048; \
        _Pragma("unroll") \
        for (int n = 0; n < 4; ++n) { \
            Bb[buf][2*n + 0] = *(const short8*)(bs_ + n * 512); \
            Bb[buf][2*n + 1] = *(const short8*)(bs_ + n * 512 + 131072); } }

    LOADA(0, 0);
    LOADB(0, 0);

    #pragma unroll
    for (int s = 0; s < 16; ++s) {
        const int cur = s & 1, nxt = cur ^ 1;
        if (s + 1 < 16) { LOADA(nxt, s + 1); LOADB(nxt, s + 1); }  // next kstep in flight

        float af0[8], af1[8];
        *(float4*)af0 = Aq[cur][0]; *(float4*)(af0 + 4) = Aq[cur][1];
        *(float4*)af1 = Aq[cur][2]; *(float4*)(af1 + 4) = Aq[cur][3];
        unsigned short p0[8], p1[8], q0[8], q1[8];
        #pragma unroll
        for (int j = 0; j < 8; ++j) {
            split2u(af0[j], p0[j], p1[j]);
            split2u(af1[j], q0[j], q1[j]);
            ssq0 = fmaf(af0[j], af0[j], ssq0);
            ssq1 = fmaf(af1[j], af1[j], ssq1);
        }
        short8 a0, a1, c0, c1;
        #pragma unroll
        for (int j = 0; j < 8; ++j) {
            a0[j] = (short)p0[j]; a1[j] = (short)p1[j];
            c0[j] = (short)q0[j]; c1[j] = (short)q1[j];
        }
        __builtin_amdgcn_s_setprio(1);
        #pragma unroll
        for (int n = 0; n < 4; ++n) {
            short8 b0 = Bb[cur][2*n + 0];
            short8 b1 = Bb[cur][2*n + 1];
            accH0[n] = mfma_f16(a0, b0, accH0[n]);
            accL0[n] = mfma_f16(a0, b1, accL0[n]);
            accL0[n] = mfma_f16(a1, b0, accL0[n]);
            accH1[n] = mfma_f16(c0, b0, accH1[n]);
            accL1[n] = mfma_f16(c0, b1, accL1[n]);
            accL1[n] = mfma_f16(c1, b0, accL1[n]);
        }
        __builtin_amdgcn_s_setprio(0);
    }
#undef LOADA
#undef LOADB

    // ssq: sum the 4 k-group lanes per token (lanes differ in bits 4,5)
    ssq0 += __shfl_xor(ssq0, 16, 64);
    ssq0 += __shfl_xor(ssq0, 32, 64);
    ssq1 += __shfl_xor(ssq1, 16, 64);
    ssq1 += __shfl_xor(ssq1, 32, 64);

    // ---- stage merged partials (s = accH + accL*2^-12) ----
    const float LSC = 1.0f / 4096.0f;
    #pragma unroll
    for (int n = 0; n < 4; ++n)
        #pragma unroll
        for (int r = 0; r < 4; ++r) {   // D: col=lane&15, row=4*(lane>>4)+reg [m89]
            Sp[kh][(4 * g + r) * 65 + 16 * n + m]      = fmaf(accL0[n][r], LSC, accH0[n][r]);
            Sp[kh][(16 + 4 * g + r) * 65 + 16 * n + m] = fmaf(accL1[n][r], LSC, accH1[n][r]);
        }
    if (l < 16) {
        SQp[kh][m]      = ssq0;
        SQp[kh][16 + m] = ssq1;
    }
    __syncthreads();

    if (tid < 32) {
        float q0 = (SQp[0][tid] + SQp[1][tid]) + (SQp[2][tid] + SQp[3][tid]);
        FN[tid] = rsqrtf(q0 * (1.0f / HDIM) + 1e-6f) * 0.022097086912079612f;
    }
    __syncthreads();

    #pragma unroll
    for (int qq = 0; qq < 2; qq++) {    // combine 4 partials: 512 float4 over 2 passes
        int f = tid + 256 * qq;
        int mr = f >> 4;
        int e4 = (f & 15) * 4;
        int base = mr * 65 + e4;
        float4 t0 = *(const float4*)&Sp[0][base];
        float4 t1 = *(const float4*)&Sp[1][base];
        float4 t2 = *(const float4*)&Sp[2][base];
        float4 t3 = *(const float4*)&Sp[3][base];
        float fn = FN[mr];
        float4 sv;
        sv.x = ((t0.x + t1.x) + (t2.x + t3.x)) * fn;
        sv.y = ((t0.y + t1.y) + (t2.y + t3.y)) * fn;
        sv.z = ((t0.z + t1.z) + (t2.z + t3.z)) * fn;
        sv.w = ((t0.w + t1.w) + (t2.w + t3.w)) * fn;
        *(float4*)&Sp[0][base] = sv;    // Sl == Sp[0]
    }
    __syncthreads();

    float* Sl = &Sp[0][0];

    // ---- proven epilogue (32 tokens) ----
    if (tid < 32) {
        const int mm = tid;
        float mx = -3.0e38f;
        for (int e = 0; e < NE; e++) mx = fmaxf(mx, Sl[mm * 65 + e]);
        float sum = 0.f;
        for (int e = 0; e < NE; e++) {
            float p = __expf(Sl[mm * 65 + e] - mx);
            Pl[mm * 65 + e] = p;
            sum += p;
        }
        RS[mm] = 1.0f / sum;
    }
    __syncthreads();

    #pragma unroll
    for (int qq = 0; qq < 2; qq++) {    // coalesced probs write: 512 float4 over 2 passes
        int f = tid + 256 * qq;
        int mr = f >> 4;
        int e0 = (f & 15) * 4;
        float rs = RS[mr];
        float4 pv;
        pv.x = Pl[mr * 65 + e0 + 0] * rs;
        pv.y = Pl[mr * 65 + e0 + 1] * rs;
        pv.z = Pl[mr * 65 + e0 + 2] * rs;
        pv.w = Pl[mr * 65 + e0 + 3] * rs;
        *(float4*)&probs[(size_t)(tok0 + mr) * NE + e0] = pv;
    }

    if (tid < 32) {                      // destructive top-4, lowest-index ties
        const int mm = tid;
        float wvv[TOPK]; int idx[TOPK];
        float wsum = 0.f;
        #pragma unroll
        for (int kk = 0; kk < TOPK; ++kk) {
            float best = -3.0e38f; int bi = 0;
            for (int e = 0; e < NE; e++) {
                float v = Sl[mm * 65 + e];
                if (v > best) { best = v; bi = e; }
            }
            Sl[mm * 65 + bi] = -3.4e38f;
            float p = Pl[mm * 65 + bi];
            wvv[kk] = p; idx[kk] = bi; wsum += p;
        }
        float inv = 1.0f / wsum;
        size_t ob = (size_t)(tok0 + mm) * TOPK;
        #pragma unroll
        for (int kk = 0; kk < TOPK; kk++) {
            tkw[ob + kk] = wvv[kk] * inv * pes[idx[kk]];
            tki[ob + kk] = (float)idx[kk];   // harness reads flat buffer as float32
        }
    }
}

extern "C" void kernel_launch(void* const* d_in, const int* in_sizes, int n_in,
                              void* d_out, int out_size, void* d_ws, size_t ws_size,
                              hipStream_t stream) {
    const float* x     = (const float*)d_in[0];
    const float* w     = (const float*)d_in[1];
    const float* scale = (const float*)d_in[2];
    const float* pes   = (const float*)d_in[3];
    const int tokens = in_sizes[0] / HDIM;      // 16384

    float* probs = (float*)d_out;
    float* tkw   = probs + (size_t)tokens * NE;
    float* tki   = tkw + (size_t)tokens * TOPK;

    unsigned short* wtb = (unsigned short*)d_ws;   // 2 planes x 256 KB = 512 KB

    prep_b_kernel<<<HDIM / 32, 256, 0, stream>>>(w, scale, wtb);

    const int grid = tokens / 32;               // 512 -> 2 blocks/CU
    fused_router_kernel<<<grid, 256, 0, stream>>>(x, wtb, pes, probs, tkw, tki);
}